// Round 6
// baseline (167.658 us; speedup 1.0000x reference)
//
#include <hip/hip_runtime.h>

#define BB 16
#define HH 512
#define WW 512
#define BH 8
#define NR (BH+5)          // 13 rows incl. halo
#define NBANDS (HH/BH)     // 64
#define NBLK (NBANDS*BB)   // 1024
#define NREG 48
#define HWTOT (HH*WW)
#define MASK13 0x1FFFu

// ws layout (bytes):
//   0        int   counts48[48][9]   (idx m*3+stat; written by pass2 blocks)
//   2048     float sums48[48][12]    (idx stat*3+m; written by pass2 blocks)
//   4608     float rankval[48]
//   4800     int   rankvalid[48]
//   5120     int   ctr               (zeroed by pass1 block (0,0))
//   8192     float sumsP[1024][40]   (per-band-block partials; [36]=sumAbs)
//   172032   int   countsP[1024][28] (per-band-block counts, idx cb*3+stat)
//   286720   u64   maskReg[48][512][8]
//   1859584  u64   maskE1 [48][512][8]
#define OFF_CNT48  0
#define OFF_SUM48  2048
#define OFF_RANKV  4608
#define OFF_RANKD  4800
#define OFF_CTR    5120
#define OFF_SUMSP  8192
#define OFF_CNTP   (OFF_SUMSP + NBLK*40*4)
#define OFF_MREG   (OFF_CNTP + NBLK*28*4)
#define MASKBYTES  (48LL*512*8*8)
#define OFF_ME1    (OFF_MREG + MASKBYTES)

__device__ __forceinline__ unsigned int hashu(unsigned int x) {
  x ^= x >> 16; x *= 0x7feb352dU; x ^= x >> 15; x *= 0x846ca68bU; x ^= x >> 16;
  return x;
}

__global__ __launch_bounds__(512, 4) void pass1_kernel(
    const float* __restrict__ pred, const float* __restrict__ target,
    const int* __restrict__ lab,
    float* __restrict__ sumsP, int* __restrict__ countsP,
    unsigned long long* __restrict__ mRegG, unsigned long long* __restrict__ mE1G,
    int* __restrict__ ctr)
{
  __shared__ unsigned long long XCH[514];
  __shared__ unsigned long long NB0[512];   // nbr windows combos 0..7 (8b each)
  __shared__ unsigned int      NB2[512];    // combo 8
  __shared__ float RED[8][37];
  __shared__ unsigned int CNT[8][14];

  const int t    = threadIdx.x;
  const int lane = t & 63;
  const int wv   = t >> 6;
  const int c    = t;
  const int r0   = blockIdx.x * BH;
  const int b    = blockIdx.y;
  const int R    = r0 - 3;
  const int bandblk = b * NBANDS + blockIdx.x;

  if (blockIdx.x == 0 && b == 0 && t == 0) *ctr = 0;   // pass2's arrival counter

  // out-of-image rows; erosion treats them as inside (clipped SAME)
  unsigned int OOR = 0;
  {
    int topClip = -R;
    if (topClip > 0) OOR |= (1u << topClip) - 1u;
    int botStart = HH - R;
    if (botStart < NR) OOR |= (~0u << botStart) & ((1u << NR) - 1u);
  }

  // ---- per-column label masks (13 bits) ----
  unsigned int colm0 = 0, colm1 = 0, colm2 = 0;
  #pragma unroll
  for (int lr = 0; lr < NR; ++lr) {
    int gy = R + lr;
    if ((unsigned)gy < (unsigned)HH) {
      int l = lab[((size_t)b*HH + gy)*WW + c];
      colm0 |= (l == 5)  ? (1u << lr) : 0u;
      colm1 |= (l == 8)  ? (1u << lr) : 0u;
      colm2 |= (l == 13) ? (1u << lr) : 0u;
    }
  }

  // ---- erosion 1 ----
  unsigned long long pk =  (unsigned long long)(colm0 | OOR)
        | ((unsigned long long)(colm1 | OOR) << 13)
        | ((unsigned long long)(colm2 | OOR) << 26);
  XCH[c+1] = pk;
  if (t == 0) { XCH[0] = ~0ull; XCH[513] = ~0ull; }
  __syncthreads();
  unsigned long long hp = pk & XCH[c] & XCH[c+2];
  unsigned int e1a[3];
  #pragma unroll
  for (int li = 0; li < 3; ++li) {
    unsigned int h = (unsigned int)((hp >> (13*li)) & MASK13);
    e1a[li] = h & (h >> 1) & (h << 1);
  }
  __syncthreads();
  // ---- erosion 2 ----
  unsigned long long pk2 =  (unsigned long long)((e1a[0] | OOR) & MASK13)
        | ((unsigned long long)((e1a[1] | OOR) & MASK13) << 13)
        | ((unsigned long long)((e1a[2] | OOR) & MASK13) << 26);
  XCH[c+1] = pk2;
  __syncthreads();
  unsigned long long hp2 = pk2 & XCH[c] & XCH[c+2];
  unsigned int e2a[3];
  #pragma unroll
  for (int li = 0; li < 3; ++li) {
    unsigned int h = (unsigned int)((hp2 >> (13*li)) & MASK13);
    e2a[li] = h & (h >> 1) & (h << 1);
  }

  unsigned int mS[9] = { colm0, e1a[0], e2a[0],
                         colm1, e1a[1], e2a[1],
                         colm2, e1a[2], e2a[2] };

  // ---- neighbor exchange: 8-bit row windows (lr 3..10) per combo ----
  {
    unsigned long long p0 = 0;
    #pragma unroll
    for (int cb = 0; cb < 8; ++cb) p0 |= (unsigned long long)((mS[cb] >> 3) & 0xFFu) << (cb*8);
    NB0[c] = p0; NB2[c] = (mS[8] >> 3) & 0xFFu;
  }
  __syncthreads();
  unsigned long long nb0 = (c < 511) ? NB0[c+1] : 0ull;
  unsigned int       nb2 = (c < 511) ? NB2[c+1] : 0u;

  // ---- packed windows: W[cb] = cell | hpair<<8 | vpair<<16 (rows 3..10) ----
  unsigned int W[9];
  const unsigned int nOOR = ~OOR;
  #pragma unroll
  for (int cb = 0; cb < 9; ++cb) {
    unsigned int w8  = (mS[cb] >> 3) & 0xFFu;
    unsigned int nbw = (cb < 8) ? ((unsigned int)(nb0 >> (cb*8)) & 0xFFu) : (nb2 & 0xFFu);
    unsigned int px8 = w8 & nbw;
    unsigned int mcl = mS[cb] & nOOR;
    unsigned int py8 = ((mcl & (mcl << 1)) >> 3) & 0xFFu;
    W[cb] = w8 | (px8 << 8) | (py8 << 16);
  }

  // ---- ballots distributed to lanes, one scatter store per wave ----
  {
    unsigned long long myWord = 0;
    #pragma unroll
    for (int k = 0; k < 48; ++k) {
      const int ktype = k / 24, krem = k % 24, kli = krem >> 3, krow = krem & 7;
      unsigned int bit = (W[kli*3 + ktype] >> krow) & 1u;
      unsigned long long wrd = __ballot(bit != 0u);
      if (lane == k) myWord = wrd;
    }
    if (lane < 48) {
      int type = lane / 24, rem = lane % 24, li = rem >> 3, row = rem & 7;
      int gy = r0 + row;
      unsigned long long* dst = type ? mE1G : mRegG;
      dst[(((size_t)(b*3 + li))*HH + gy)*8 + wv] = myWord;
    }
  }

  // ---- counts packed 2x16-bit, wave shfl reduce ----
  {
    unsigned int pkc[14];
    #pragma unroll
    for (int j = 0; j < 14; ++j) pkc[j] = 0;
    #pragma unroll
    for (int cb = 0; cb < 9; ++cb) {
      unsigned int cnt = __popc(W[cb] & 0x0000FFu);
      unsigned int cx  = __popc(W[cb] & 0x00FF00u);
      unsigned int cy  = __popc(W[cb] & 0xFF0000u);
      int k0 = cb*3;
      pkc[(k0  )>>1] |= cnt << (((k0  )&1)*16);
      pkc[(k0+1)>>1] |= cx  << (((k0+1)&1)*16);
      pkc[(k0+2)>>1] |= cy  << (((k0+2)&1)*16);
    }
    #pragma unroll
    for (int j = 0; j < 14; ++j) {
      unsigned int v = pkc[j];
      for (int off = 32; off; off >>= 1) v += __shfl_down(v, off);
      if (lane == 0) CNT[wv][j] = v;
    }
  }

  // ---- stats row loop: 3 bfe + 3 cndmask + 3 add + 1 fma per combo ----
  float aP[9] = {}, aP2[9] = {}, aDX[9] = {}, aDY[9] = {};
  float aAbs = 0.f;
  const float* pB = pred   + (size_t)b*HH*WW;
  const float* tB = target + (size_t)b*HH*WW;
  float p_prev = (r0 > 0) ? pB[(size_t)(r0-1)*WW + c] : 0.f;
  const int cR = (c < 511) ? c + 1 : c;

  #pragma unroll
  for (int row = 0; row < BH; ++row) {
    const int gy = r0 + row;
    const float* prow = pB + (size_t)gy*WW;
    float p  = prow[c];
    float pr = prow[cR];
    float tg = tB[(size_t)gy*WW + c];
    aAbs += fabsf(p - tg);
    float d = fabsf(pr - p);
    float v = fabsf(p - p_prev);
    #pragma unroll
    for (int cb = 0; cb < 9; ++cb) {
      unsigned int c1 = (W[cb] >> row) & 1u;
      unsigned int px = (W[cb] >> (row + 8)) & 1u;
      unsigned int py = (W[cb] >> (row + 16)) & 1u;
      float f = c1 ? p : 0.f;
      aP[cb]  += f;
      aP2[cb]  = fmaf(f, p, aP2[cb]);
      aDX[cb] += px ? d : 0.f;
      aDY[cb] += py ? v : 0.f;     // py already excludes gy==0 (OOR-cleared)
    }
    p_prev = p;
  }

  // ---- wave reduce floats -> LDS ----
  #pragma unroll
  for (int cb = 0; cb < 9; ++cb) {
    float s0 = aP[cb], s1 = aP2[cb], s2 = aDX[cb], s3 = aDY[cb];
    for (int off = 32; off; off >>= 1) {
      s0 += __shfl_down(s0, off);
      s1 += __shfl_down(s1, off);
      s2 += __shfl_down(s2, off);
      s3 += __shfl_down(s3, off);
    }
    if (lane == 0) {
      RED[wv][0*9 + cb] = s0; RED[wv][1*9 + cb] = s1;
      RED[wv][2*9 + cb] = s2; RED[wv][3*9 + cb] = s3;
    }
  }
  {
    float va = aAbs;
    for (int off = 32; off; off >>= 1) va += __shfl_down(va, off);
    if (lane == 0) RED[wv][36] = va;
  }
  __syncthreads();

  // ---- per-block partial outputs (plain stores, no atomics) ----
  if (t < 37) {
    float s = 0.f;
    #pragma unroll
    for (int w = 0; w < 8; ++w) s += RED[w][t];
    sumsP[(size_t)bandblk*40 + t] = s;
  }
  if (t < 14) {
    unsigned int s = 0;
    #pragma unroll
    for (int w = 0; w < 8; ++w) s += CNT[w][t];
    countsP[bandblk*28 + 2*t]     = (int)(s & 0xFFFFu);
    countsP[bandblk*28 + 2*t + 1] = (int)(s >> 16);
  }
}

__global__ __launch_bounds__(256) void pass2_kernel(
    const float* __restrict__ pred, const float* __restrict__ img1,
    const float* __restrict__ img2,
    const unsigned long long* __restrict__ mRegG,
    const unsigned long long* __restrict__ mE1G,
    const float* __restrict__ sumsP, const int* __restrict__ countsP,
    int* __restrict__ counts48, float* __restrict__ sums48,
    float* __restrict__ rankval, int* __restrict__ rankvalid,
    int* __restrict__ ctr, float* __restrict__ out)
{
  const int r = blockIdx.x;       // 0..47
  const int b = r / 3, li = r % 3;
  const int t = threadIdx.x;
  const int lane = t & 63;
  const int wv   = t >> 6;
  __shared__ int LC[9];           // my region counts, idx m*3+stat
  __shared__ int rowc[HH];
  __shared__ int pre[HH];
  __shared__ int grpPre[64];
  __shared__ int idxArr[200];
  __shared__ float redH[4];
  __shared__ int   redP[4];
  __shared__ int lastFlag;
  __shared__ double svvS[NREG], smvS[NREG];
  __shared__ int svdS[NREG], smdS[NREG];
  __shared__ double SAB[4];

  if (t < 9) LC[t] = 0;
  __syncthreads();
  for (int k = t; k < 9*NBANDS; k += 256) {
    int s9 = k >> 6, band = k & 63;
    int m = s9 / 3, st = s9 % 3;
    atomicAdd(&LC[s9], countsP[(b*NBANDS + band)*28 + (li*3 + m)*3 + st]);
  }
  // sums reduce (wave 0: lane = band), write device-coherent
  if (wv == 0) {
    float sp[12];
    #pragma unroll
    for (int j = 0; j < 12; ++j) {
      int stat = j / 3, m = j % 3;
      sp[j] = sumsP[(size_t)(b*NBANDS + lane)*40 + stat*9 + li*3 + m];
    }
    #pragma unroll
    for (int j = 0; j < 12; ++j)
      for (int off = 32; off; off >>= 1) sp[j] += __shfl_down(sp[j], off);
    if (lane == 0) {
      #pragma unroll
      for (int j = 0; j < 12; ++j) atomicExch(&sums48[r*12 + j], sp[j]);
    }
  }
  __syncthreads();
  if (t < 9) atomicExch(&counts48[r*9 + t], LC[t]);

  int n_reg = LC[0], n_e1 = LC[3];
  int useE1 = (n_e1 >= 2);
  int n1 = useE1 ? n_e1 : n_reg;
  bool doRank = (n_reg >= 2 && n1 >= 2);
  float rv = 0.f; int rvd = 0;

  if (doRank) {
    const unsigned long long* M = (useE1 ? mE1G : mRegG) + (size_t)r*HH*8;
    {
      int row = t*2;
      int c0 = 0, c1v = 0;
      #pragma unroll
      for (int w = 0; w < 8; ++w) c0 += __popcll(M[(size_t)row*8 + w]);
      #pragma unroll
      for (int w = 0; w < 8; ++w) c1v += __popcll(M[(size_t)(row+1)*8 + w]);
      rowc[row] = c0; rowc[row+1] = c1v;
    }
    __syncthreads();
    if (t < 64) {
      int base = t*8, s = 0;
      #pragma unroll
      for (int k = 0; k < 8; ++k) s += rowc[base + k];
      int v = s;
      for (int off = 1; off < 64; off <<= 1) {
        int o = __shfl_up(v, off);
        if (t >= off) v += o;
      }
      grpPre[t] = v - s;
    }
    __syncthreads();
    if (t < 64) {
      int s = grpPre[t], base = t*8;
      #pragma unroll
      for (int k = 0; k < 8; ++k) { pre[base + k] = s; s += rowc[base + k]; }
    }
    __syncthreads();

    if (t < 200) {
      unsigned int h = hashu(0x9e3779b9u + (unsigned)(r*200 + t));
      float u = (float)(h >> 8) * (1.0f / 16777216.0f);
      int k = (int)(u * (float)n1);
      if (k >= n1) k = n1 - 1;
      if (k < 0) k = 0;
      int lo = 0, hi = HH;
      while (hi - lo > 1) { int mid = (lo + hi) >> 1; if (pre[mid] <= k) lo = mid; else hi = mid; }
      int row = lo;
      int local = k - pre[row];
      int idx = 0;
      #pragma unroll
      for (int w = 0; w < 8; ++w) {
        unsigned long long mm = M[(size_t)row*8 + w];
        int cc = __popcll(mm);
        if (local < cc) {
          for (int i = 0; i < local; ++i) mm &= mm - 1;
          idx = row*WW + w*64 + __builtin_ctzll(mm);
          local = 1 << 20;
        } else {
          local -= cc;
        }
      }
      idxArr[t] = idx;
    }
    __syncthreads();

    float hv = 0.f; int pv = 0;
    if (t < 100) {
      int ii = idxArr[t], jj = idxArr[t+100];
      size_t base = (size_t)b * HWTOT;
      float pi = pred[base+ii], pj = pred[base+jj];
      float xi = 0.5f*(1.f - img1[base+ii]) + 0.5f*img2[base+ii];
      float xj = 0.5f*(1.f - img1[base+jj]) + 0.5f*img2[base+jj];
      float s = (xi > xj) ? 1.f : ((xi < xj) ? -1.f : 0.f);
      pv = (ii != jj) && (s != 0.f);
      float hinge = fmaxf(0.f, -(pi - pj)*s);
      hv = pv ? hinge : 0.f;
    }
    for (int off = 32; off; off >>= 1) {
      hv += __shfl_down(hv, off);
      pv += __shfl_down(pv, off);
    }
    if (lane == 0) { redH[wv] = hv; redP[wv] = pv; }
    __syncthreads();
    if (t == 0) {
      float sh = redH[0] + redH[1] + redH[2] + redH[3];
      int   sp = redP[0] + redP[1] + redP[2] + redP[3];
      rv  = sh / (float)(sp > 0 ? sp : 1);
      rvd = (sp > 0) ? 1 : 0;
    }
  }

  __syncthreads();   // ensure counts48/sums48 exchanges drained before arrival
  if (t == 0) {
    atomicExch(&rankval[r], rv);
    atomicExch(&rankvalid[r], rvd);
    __threadfence();
    int old = atomicAdd(ctr, 1);
    lastFlag = (old == NREG - 1);
  }
  __syncthreads();

  if (lastFlag) {
    __threadfence();   // acquire
    // global |pred-target| sum over all 1024 band-blocks
    double pa = 0.0;
    for (int k = t; k < NBLK; k += 256) pa += (double)sumsP[(size_t)k*40 + 36];
    for (int off = 32; off; off >>= 1) pa += __shfl_down(pa, off);
    if (lane == 0) SAB[wv] = pa;
    if (t < NREG) {
      const int* C = counts48 + t*9;       // C[m*3+stat]
      const float* S = sums48 + t*12;      // S[stat*3+m]
      int nr = C[0], ne1 = C[3], ne2 = C[6];
      int m1 = (ne1 < 2) ? 0 : 1;
      int m2 = (ne2 < 3) ? m1 : 2;
      int n2 = C[m2*3];
      double n2s = (double)(n2 > 1 ? n2 : 1);
      double mu  = (double)S[m2] / n2s;
      double var = (double)S[3+m2] / n2s - mu*mu;
      if (var < 0.0) var = 0.0;
      double cv = sqrt(var) / (fabs(mu) + 1e-6);
      int tli = t % 3;
      double tcv = (tli == 0) ? 0.077 : ((tli == 1) ? 0.227 : 0.348);
      svvS[t] = fabs(cv - tcv);
      svdS[t] = (nr >= 3 && n2 >= 3);
      int cx = C[m2*3+1], cy = C[m2*3+2];
      double mean_x = (double)S[6+m2] / (double)(cx > 1 ? cx : 1);
      double mean_y = (double)S[9+m2] / (double)(cy > 1 ? cy : 1);
      int hx = (cx > 0), hy = (cy > 0);
      int npres = hx + hy;
      smvS[t] = (mean_x*hx + mean_y*hy) / (double)(npres > 1 ? npres : 1);
      smdS[t] = (nr >= 3 && n2 >= 3 && npres > 0);
    }
    __syncthreads();
    if (t == 0) {
      double s_std = 0, s_sm = 0, s_rk = 0;
      int c_std = 0, c_sm = 0, c_rk = 0;
      for (int i = 0; i < NREG; ++i) {
        if (svdS[i])       { s_std += svvS[i];     c_std++; }
        if (smdS[i])       { s_sm  += smvS[i];     c_sm++;  }
        if (rankvalid[i])  { s_rk  += rankval[i];  c_rk++;  }
      }
      double loss_std = c_std ? s_std / c_std : 0.0;
      double loss_sm  = c_sm  ? s_sm  / c_sm  : 0.0;
      double loss_rk  = c_rk  ? s_rk  / c_rk  : 0.0;
      double loss_mean = (SAB[0] + SAB[1] + SAB[2] + SAB[3])
                         / (double)((long long)BB * HWTOT);
      out[0] = (float)(0.5*loss_mean + 0.5*loss_std + loss_rk + loss_sm);
    }
  }
}

extern "C" void kernel_launch(void* const* d_in, const int* in_sizes, int n_in,
                              void* d_out, int out_size, void* d_ws, size_t ws_size,
                              hipStream_t stream) {
  const float* pred   = (const float*)d_in[0];
  const float* target = (const float*)d_in[1];
  const int*   lab    = (const int*)d_in[2];
  const float* img1   = (const float*)d_in[3];
  const float* img2   = (const float*)d_in[4];
  float* out = (float*)d_out;
  char* ws = (char*)d_ws;

  int*    counts48 = (int*)(ws + OFF_CNT48);
  float*  sums48   = (float*)(ws + OFF_SUM48);
  float*  rankval  = (float*)(ws + OFF_RANKV);
  int*    rankvld  = (int*)(ws + OFF_RANKD);
  int*    ctr      = (int*)(ws + OFF_CTR);
  float*  sumsP    = (float*)(ws + OFF_SUMSP);
  int*    countsP  = (int*)(ws + OFF_CNTP);
  unsigned long long* mReg = (unsigned long long*)(ws + OFF_MREG);
  unsigned long long* mE1  = (unsigned long long*)(ws + OFF_ME1);

  dim3 g1(NBANDS, BB);
  pass1_kernel<<<g1, 512, 0, stream>>>(pred, target, lab, sumsP, countsP,
                                       mReg, mE1, ctr);
  pass2_kernel<<<NREG, 256, 0, stream>>>(pred, img1, img2, mReg, mE1,
                                         sumsP, countsP, counts48, sums48,
                                         rankval, rankvld, ctr, out);
}